// Round 3
// baseline (1026.023 us; speedup 1.0000x reference)
//
#include <hip/hip_runtime.h>
#include <math.h>

#define NT 2048
#define HID 768
#define NC 40960
#define NFEAT 20
#define UN 1024
#define SDIM 2324
#define NTOP 512
#define WMAX 20
#define TOPT 8192

// prefix-scan geometry: 1793 weighted columns (768 hidden | 1024 Pd | 1 Z)
#define NCOLS 1793
#define CHUNK 64
#define NCHUNK 32
#define CS_STRIDE 1800

// d_out element offsets (all f32)
#define OFF_IDX   95191040
#define OFF_S     95191552
#define OFF_E     95192064
#define OFF_PEMB  95192576
#define OFF_SC    96382464
#define OFF_SP    96382976

// ---------------- generic zero ----------------
__global__ void k_zero(int* __restrict__ p, int n) {
  int i = blockIdx.x * 256 + threadIdx.x;
  if (i < n) p[i] = 0;
}

// ---------------- fused setup: hist | tok_att(expA) | Pc | prior ----------------
// blocks [0,160): hist; [160,672): expA; [672,752): Pc; [752,772): prior
__global__ __launch_bounds__(256) void k_setup(
    const int* __restrict__ starts, int* __restrict__ hist,
    const float* __restrict__ hidden, const float* __restrict__ w_attn,
    const float* __restrict__ b_attn, float* __restrict__ expA,
    const float* __restrict__ emb_width, const float* __restrict__ W1,
    float* __restrict__ Pc,
    const float* __restrict__ ewp, const float* __restrict__ Wp1,
    const float* __restrict__ bp1, const float* __restrict__ Wp2,
    const float* __restrict__ bp2, float* __restrict__ prior) {
  __shared__ float red[256];
  int b = blockIdx.x;
  int tid = threadIdx.x;
  if (b < 160) {                       // hist
    int i = b * 256 + tid;
    atomicAdd(&hist[starts[i]], 1);
    return;
  }
  b -= 160;
  if (b < 512) {                       // expA: one wave per token
    int wave = (b * 256 + tid) >> 6;
    int lane = tid & 63;
    if (wave >= NT) return;
    const float* row = hidden + (size_t)wave * HID;
    float s = 0.f;
    for (int c = lane; c < HID; c += 64) s += row[c] * w_attn[c];
    #pragma unroll
    for (int off = 32; off; off >>= 1) s += __shfl_down(s, off);
    if (lane == 0) expA[wave] = expf(s + b_attn[0]);
    return;
  }
  b -= 512;
  if (b < 80) {                        // Pc[w][j] = emb_width[w] @ W1 rows [1536,1556)
    int idx = b * 256 + tid;
    int w = idx >> 10, j = idx & 1023;
    float s = 0.f;
    #pragma unroll
    for (int k = 0; k < NFEAT; ++k) s += emb_width[w * NFEAT + k] * W1[(size_t)(2 * HID + k) * UN + j];
    Pc[idx] = s;
    return;
  }
  b -= 80;
  {                                    // prior[w]
    int w = b;
    float local = 0.f;
    for (int j = tid; j < UN; j += 256) {
      float hp = bp1[j];
      #pragma unroll
      for (int k = 0; k < NFEAT; ++k) hp += ewp[w * NFEAT + k] * Wp1[k * UN + j];
      local += fmaxf(hp, 0.f) * Wp2[j];
    }
    red[tid] = local;
    __syncthreads();
    for (int st = 128; st > 0; st >>= 1) { if (tid < st) red[tid] += red[tid + st]; __syncthreads(); }
    if (tid == 0) prior[w] = red[0] + bp2[0];
  }
}

// ---------------- prefix over hist -> cursor (running) + bases (fixed) ----------------
__global__ __launch_bounds__(256) void k_prefix(const int* __restrict__ hist,
                                                int* __restrict__ cursor,
                                                int* __restrict__ bases) {
  __shared__ int tsum[256];
  int tid = threadIdx.x;
  int v[8], pre[8];
  int s = 0;
  #pragma unroll
  for (int j = 0; j < 8; ++j) { v[j] = hist[tid * 8 + j]; pre[j] = s; s += v[j]; }
  tsum[tid] = s;
  __syncthreads();
  for (int off = 1; off < 256; off <<= 1) {
    int t = (tid >= off) ? tsum[tid - off] : 0;
    __syncthreads();
    tsum[tid] += t;
    __syncthreads();
  }
  int base = (tid > 0) ? tsum[tid - 1] : 0;
  #pragma unroll
  for (int j = 0; j < 8; ++j) {
    cursor[tid * 8 + j] = base + pre[j];
    bases[tid * 8 + j] = base + pre[j];
  }
  if (tid == 255) bases[2048] = NC;
}

__global__ void k_place(const int* __restrict__ starts, int* __restrict__ cursor,
                        int* __restrict__ ord) {
  int i = blockIdx.x * 256 + threadIdx.x;
  int pos = atomicAdd(&cursor[starts[i]], 1);
  ord[pos] = i;
}

// ---------------- P = hidden @ [W1a | W1b | W1d]  (2048 x 3072, K=768) ----------------
__global__ __launch_bounds__(256) void k_matmul_P(const float* __restrict__ hidden,
                                                  const float* __restrict__ W1,
                                                  float* __restrict__ P) {
  __shared__ float As[16][132];
  __shared__ float Bs[16][128];
  int bn = blockIdx.x, bm = blockIdx.y;
  int n0 = bn * 128;
  int seg = n0 >> 10;
  int rowbase = (seg == 0) ? 0 : (seg == 1 ? HID : (2 * HID + NFEAT));
  int j0 = n0 & 1023;
  int tid = threadIdx.x;
  int tx = tid & 15, ty = tid >> 4;
  float acc[8][8] = {};
  for (int k0 = 0; k0 < HID; k0 += 16) {
    #pragma unroll
    for (int q = 0; q < 2; ++q) {
      int idx = q * 256 + tid;
      int m = idx >> 2, kg = idx & 3;
      float4 a = *(const float4*)&hidden[(size_t)(bm * 128 + m) * HID + k0 + kg * 4];
      As[kg * 4 + 0][m] = a.x; As[kg * 4 + 1][m] = a.y;
      As[kg * 4 + 2][m] = a.z; As[kg * 4 + 3][m] = a.w;
      int k = idx >> 5, ng = idx & 31;
      float4 b = *(const float4*)&W1[(size_t)(rowbase + k0 + k) * UN + j0 + ng * 4];
      *(float4*)&Bs[k][ng * 4] = b;
    }
    __syncthreads();
    #pragma unroll
    for (int k = 0; k < 16; ++k) {
      float4 a0 = *(const float4*)&As[k][ty * 8];
      float4 a1 = *(const float4*)&As[k][ty * 8 + 4];
      float4 b0 = *(const float4*)&Bs[k][tx * 8];
      float4 b1 = *(const float4*)&Bs[k][tx * 8 + 4];
      float av[8] = {a0.x, a0.y, a0.z, a0.w, a1.x, a1.y, a1.z, a1.w};
      float bv[8] = {b0.x, b0.y, b0.z, b0.w, b1.x, b1.y, b1.z, b1.w};
      #pragma unroll
      for (int i = 0; i < 8; ++i)
        #pragma unroll
        for (int jj = 0; jj < 8; ++jj) acc[i][jj] += av[i] * bv[jj];
    }
    __syncthreads();
  }
  #pragma unroll
  for (int i = 0; i < 8; ++i) {
    float* prow = &P[(size_t)(bm * 128 + ty * 8 + i) * 3072 + n0 + tx * 8];
    *(float4*)prow = make_float4(acc[i][0], acc[i][1], acc[i][2], acc[i][3]);
    *(float4*)(prow + 4) = make_float4(acc[i][4], acc[i][5], acc[i][6], acc[i][7]);
  }
}

// ---------------- weighted prefix scan over [hidden(768) | Pd(1024) | 1] ----------------
__global__ __launch_bounds__(256) void k_psumA(const float* __restrict__ hidden,
                                               const float* __restrict__ P,
                                               const float* __restrict__ expA,
                                               double* __restrict__ chunkSum) {
  int col = blockIdx.x * 256 + threadIdx.x;
  int ch = blockIdx.y;
  if (col >= NCOLS) return;
  double acc = 0.0;
  int t0 = ch * CHUNK;
  if (col < HID) {
    const float* p = hidden + col;
    #pragma unroll 8
    for (int r = 0; r < CHUNK; ++r) {
      int t = t0 + r;
      acc += (double)expA[t] * (double)p[(size_t)t * HID];
    }
  } else if (col < HID + UN) {
    const float* p = P + 2048 + (col - HID);
    #pragma unroll 8
    for (int r = 0; r < CHUNK; ++r) {
      int t = t0 + r;
      acc += (double)expA[t] * (double)p[(size_t)t * 3072];
    }
  } else {
    #pragma unroll 8
    for (int r = 0; r < CHUNK; ++r) acc += (double)expA[t0 + r];
  }
  chunkSum[(size_t)ch * CS_STRIDE + col] = acc;
}

__global__ __launch_bounds__(256) void k_psumB(double* __restrict__ chunkSum,
                                               double* __restrict__ prefH,
                                               double* __restrict__ prefPd,
                                               double* __restrict__ prefZ) {
  int col = blockIdx.x * 256 + threadIdx.x;
  if (col >= NCOLS) return;
  double run = 0.0;
  for (int ch = 0; ch < NCHUNK; ++ch) {
    size_t o = (size_t)ch * CS_STRIDE + col;
    double v = chunkSum[o];
    chunkSum[o] = run;
    run += v;
  }
  if (col < HID) prefH[col] = 0.0;
  else if (col < HID + UN) prefPd[col - HID] = 0.0;
  else prefZ[0] = 0.0;
}

__global__ __launch_bounds__(256) void k_psumC(const float* __restrict__ hidden,
                                               const float* __restrict__ P,
                                               const float* __restrict__ expA,
                                               const double* __restrict__ chunkSum,
                                               double* __restrict__ prefH,
                                               double* __restrict__ prefPd,
                                               double* __restrict__ prefZ) {
  int col = blockIdx.x * 256 + threadIdx.x;
  int ch = blockIdx.y;
  if (col >= NCOLS) return;
  double acc = chunkSum[(size_t)ch * CS_STRIDE + col];
  int t0 = ch * CHUNK;
  if (col < HID) {
    const float* p = hidden + col;
    double* o = prefH + col;
    #pragma unroll 4
    for (int r = 0; r < CHUNK; ++r) {
      int t = t0 + r;
      acc += (double)expA[t] * (double)p[(size_t)t * HID];
      o[(size_t)(t + 1) * HID] = acc;
    }
  } else if (col < HID + UN) {
    int c = col - HID;
    const float* p = P + 2048 + c;
    double* o = prefPd + c;
    #pragma unroll 4
    for (int r = 0; r < CHUNK; ++r) {
      int t = t0 + r;
      acc += (double)expA[t] * (double)p[(size_t)t * 3072];
      o[(size_t)(t + 1) * UN] = acc;
    }
  } else {
    #pragma unroll 4
    for (int r = 0; r < CHUNK; ++r) {
      int t = t0 + r;
      acc += (double)expA[t];
      prefZ[t + 1] = acc;
    }
  }
}

// ---------------- grouped span_emb + score: one block per start token ----------------
// candidates with start s are ord[bases[s] .. bases[s+1]); per-block invariants
// (b1, Pa[s], W2, prefPd[s], prefZ[s]) hoisted to registers. Arithmetic is
// bit-identical to the previous per-candidate kernel.
__global__ __launch_bounds__(256) void k_span2(
    const int* __restrict__ ord, const int* __restrict__ bases,
    const float* __restrict__ hidden, const int* __restrict__ ends,
    const float* __restrict__ emb_width,
    const double* __restrict__ prefH, const double* __restrict__ prefPd,
    const double* __restrict__ prefZ,
    const float* __restrict__ P, const float* __restrict__ Pc,
    const float* __restrict__ b1, const float* __restrict__ W2,
    const float* __restrict__ b2ptr, const float* __restrict__ prior,
    float* __restrict__ out, float* __restrict__ scores,
    unsigned long long* __restrict__ keys, int* __restrict__ hist64k) {
  int s = blockIdx.x;
  int c0 = bases[s], c1 = bases[s + 1];
  if (c0 >= c1) return;
  int tid = threadIdx.x;
  int j = tid * 4;
  __shared__ float red[4];
  // per-block invariants
  float4 bb = *(const float4*)(b1 + j);
  float4 pa = *(const float4*)(P + (size_t)s * 3072 + j);
  float4 w2 = *(const float4*)(W2 + j);
  const double* pdsp = prefPd + (size_t)s * UN + j;
  double pds0 = pdsp[0], pds1 = pdsp[1], pds2 = pdsp[2], pds3 = pdsp[3];
  double zs = prefZ[s];
  const float* hs = hidden + (size_t)s * HID;
  const double* pHs = prefH + (size_t)s * HID;
  float b2v = b2ptr[0];

  for (int c = c0; c < c1; ++c) {
    int i = ord[c];
    int e = ends[i];
    int w = e - s;
    double invZ = 1.0 / (prefZ[e + 1] - zs);
    const float* he = hidden + (size_t)e * HID;
    const double* pHe = prefH + (size_t)(e + 1) * HID;
    float* orow = out + (size_t)i * SDIM;
    for (int q = tid; q < SDIM / 4; q += 256) {
      int cc = q * 4;
      float4 v;
      if (cc < HID) v = *(const float4*)(hs + cc);
      else if (cc < 2 * HID) v = *(const float4*)(he + (cc - HID));
      else if (cc < 2 * HID + NFEAT) v = *(const float4*)(emb_width + w * NFEAT + (cc - 2 * HID));
      else {
        int cx = cc - (2 * HID + NFEAT);
        const double* pe = pHe + cx;
        const double* ps = pHs + cx;
        v = make_float4((float)((pe[0] - ps[0]) * invZ),
                        (float)((pe[1] - ps[1]) * invZ),
                        (float)((pe[2] - ps[2]) * invZ),
                        (float)((pe[3] - ps[3]) * invZ));
      }
      *(float4*)(orow + cc) = v;
    }
    // score: pre_h = b1 + Pa[s] + Pb[e] + Pc[w] + (prefPd[e+1]-prefPd[s])/Z
    float4 pb = *(const float4*)(P + (size_t)e * 3072 + 1024 + j);
    float4 pc = *(const float4*)(Pc + w * UN + j);
    const double* pde = prefPd + (size_t)(e + 1) * UN + j;
    float4 pre;
    pre.x = bb.x + (pa.x + pb.x + pc.x + (float)((pde[0] - pds0) * invZ));
    pre.y = bb.y + (pa.y + pb.y + pc.y + (float)((pde[1] - pds1) * invZ));
    pre.z = bb.z + (pa.z + pb.z + pc.z + (float)((pde[2] - pds2) * invZ));
    pre.w = bb.w + (pa.w + pb.w + pc.w + (float)((pde[3] - pds3) * invZ));
    float local = fmaxf(pre.x, 0.f) * w2.x + fmaxf(pre.y, 0.f) * w2.y +
                  fmaxf(pre.z, 0.f) * w2.z + fmaxf(pre.w, 0.f) * w2.w;
    #pragma unroll
    for (int off = 32; off; off >>= 1) local += __shfl_down(local, off);
    if ((tid & 63) == 0) red[tid >> 6] = local;
    __syncthreads();
    if (tid == 0) {
      float sc = red[0] + red[1] + red[2] + red[3] + b2v + prior[w];
      scores[i] = sc;
      unsigned u = __float_as_uint(sc);
      u = (u >> 31) ? ~u : (u | 0x80000000u);        // ascending-order map
      unsigned inv = ~u;                             // descending score
      keys[i] = (((unsigned long long)inv) << 32) | (unsigned)i;
      atomicAdd(&hist64k[(int)(inv >> 16)], 1);      // fused bucket histogram
    }
    __syncthreads();
  }
}

// ---------------- find smallest bucket B with cum(<=B) >= TOPT ----------------
__global__ __launch_bounds__(1024) void k_cutoff(const int* __restrict__ hist64k,
                                                 int* __restrict__ cutB) {
  __shared__ int psum[1024];
  int tid = threadIdx.x;
  int base = tid * 64;
  int s = 0;
  #pragma unroll
  for (int j = 0; j < 16; ++j) {
    int4 v = *(const int4*)&hist64k[base + j * 4];
    s += v.x + v.y + v.z + v.w;
  }
  psum[tid] = s;
  __syncthreads();
  for (int off = 1; off < 1024; off <<= 1) {
    int t = (tid >= off) ? psum[tid - off] : 0;
    __syncthreads();
    psum[tid] += t;
    __syncthreads();
  }
  int cumEnd = psum[tid];
  int cumStart = cumEnd - s;
  if (cumStart < TOPT && TOPT <= cumEnd) {
    int run = cumStart;
    for (int j = 0; j < 64; ++j) {
      run += hist64k[base + j];
      if (run >= TOPT) { cutB[0] = base + j; break; }
    }
  }
}

__global__ void k_compact(const unsigned long long* __restrict__ keys,
                          const int* __restrict__ cutB,
                          int* __restrict__ survCount,
                          int* __restrict__ surv,
                          unsigned long long* __restrict__ survKey) {
  int i = blockIdx.x * 256 + threadIdx.x;
  int B = cutB[0];
  unsigned long long k = keys[i];
  bool keep = ((int)(k >> 48)) <= B;
  unsigned long long m = __ballot(keep);
  if (m == 0ull) return;
  int lane = threadIdx.x & 63;
  int leader = __ffsll((long long)m) - 1;
  int pos = 0;
  if (lane == leader) pos = atomicAdd(survCount, __popcll(m));
  pos = __shfl(pos, leader);
  if (keep) {
    int slot = pos + __popcll(m & ((1ull << lane) - 1ull));
    surv[slot] = i;
    survKey[slot] = k;
  }
}

// exact rank among survivors (S ~ TOPT + one-bucket slack)
__global__ __launch_bounds__(256) void k_rankT(const unsigned long long* __restrict__ survKey,
                                               const int* __restrict__ survCount,
                                               int* __restrict__ rankS) {
  int S = survCount[0];
  int i = blockIdx.x * 256 + threadIdx.x;
  int j0 = blockIdx.y * 1280;
  if (i >= S || j0 >= S) return;
  int j1 = min(j0 + 1280, S);
  unsigned long long mk = survKey[i];
  int cnt = 0;
  for (int j = j0; j < j1; ++j) cnt += (survKey[j] < mk) ? 1 : 0;
  if (cnt) atomicAdd(&rankS[i], cnt);
}

__global__ void k_scatterT(const int* __restrict__ surv, const int* __restrict__ rankS,
                           const int* __restrict__ survCount, int* __restrict__ order) {
  int t = blockIdx.x * 256 + threadIdx.x;
  if (t < survCount[0]) order[rankS[t]] = surv[t];
}

// ---------------- greedy NMS over top-S survivors, survivor-skip serial loop --------
__global__ void k_scanT(const int* __restrict__ order,
                        const int* __restrict__ starts,
                        const int* __restrict__ ends,
                        const int* __restrict__ survCount,
                        int* __restrict__ acc_idx, int* __restrict__ acc_s,
                        int* __restrict__ acc_e, int* __restrict__ acc_count,
                        int* __restrict__ flag) {
  __shared__ int LE[NT];
  __shared__ int ES[NT];
  int lane = threadIdx.x;
  int S = survCount[0];
  for (int t = lane; t < NT; t += 64) { LE[t] = -1; ES[t] = NT; }
  __syncthreads();
  int count = 0;
  for (int base = 0; base < S && count < NTOP; base += 64) {
    int idx = base + lane;
    bool valid = idx < S;
    int ci = order[valid ? idx : 0];
    int sv = starts[ci];
    int ev = ends[ci];
    bool pc = !valid;
    for (int t = sv; t <= ev; ++t) {
      int l = LE[t], es2 = ES[t];
      pc = pc || ((t > sv) && (l > ev)) || ((t < ev) && (es2 < sv));
    }
    unsigned long long rem = ~__ballot(pc);
    int localCount = 0;
    int ls = 0, le = -1, li = 0;
    while (rem != 0ull && count < NTOP) {
      int t = __ffsll((long long)rem) - 1;
      rem &= rem - 1;
      int s = __shfl(sv, t);
      int e = __shfl(ev, t);
      int cidx = __shfl(ci, t);
      bool ov = (lane < localCount) &&
                (((s < ls) && (ls <= e) && (e < le)) ||
                 ((ls < s) && (s <= le) && (le < e)));
      if (!__any(ov)) {
        if (lane == localCount) { ls = s; le = e; li = cidx; }
        localCount++;
        count++;
      }
    }
    int cbase = count - localCount;
    if (lane < localCount) {
      acc_idx[cbase + lane] = li;
      acc_s[cbase + lane] = ls;
      acc_e[cbase + lane] = le;
      atomicMax(&LE[ls], le);
      atomicMin(&ES[le], ls);
    }
    __syncthreads();
  }
  if (lane == 0) {
    acc_count[0] = count;
    flag[0] = (count < NTOP && S < NC) ? 1 : 0;
  }
}

// ---------------- fallback path (flag-gated; ~never runs) ----------------
__global__ __launch_bounds__(256) void k_rank_fb(const int* __restrict__ flag,
                                                 const unsigned long long* __restrict__ keys,
                                                 int* __restrict__ rank2) {
  if (!flag[0]) return;
  int ic = blockIdx.x >> 5;
  int jc = blockIdx.x & 31;
  int tid = threadIdx.x;
  int ibase = ic * 2048 + tid;
  unsigned long long mk[8];
  int cnt[8];
  #pragma unroll
  for (int k = 0; k < 8; ++k) { mk[k] = keys[ibase + k * 256]; cnt[k] = 0; }
  int j0 = jc * 1280;
  #pragma unroll 4
  for (int j = j0; j < j0 + 1280; ++j) {
    unsigned long long kj = keys[j];
    #pragma unroll
    for (int k = 0; k < 8; ++k) cnt[k] += (kj < mk[k]) ? 1 : 0;
  }
  #pragma unroll
  for (int k = 0; k < 8; ++k) if (cnt[k]) atomicAdd(&rank2[ibase + k * 256], cnt[k]);
}

__global__ void k_scatter_fb(const int* __restrict__ flag, const int* __restrict__ rank2,
                             int* __restrict__ orderFB) {
  if (!flag[0]) return;
  int i = blockIdx.x * 256 + threadIdx.x;
  orderFB[rank2[i]] = i;
}

__global__ void k_scan_fb(const int* __restrict__ flag,
                          const int* __restrict__ orderFB,
                          const int* __restrict__ starts,
                          const int* __restrict__ ends,
                          int* __restrict__ acc_idx, int* __restrict__ acc_s,
                          int* __restrict__ acc_e, int* __restrict__ acc_count) {
  if (!flag[0]) return;
  __shared__ int LE[NT];
  __shared__ int ES[NT];
  int lane = threadIdx.x;
  for (int t = lane; t < NT; t += 64) { LE[t] = -1; ES[t] = NT; }
  __syncthreads();
  int count = 0;
  for (int base = 0; base < NC && count < NTOP; base += 64) {
    int ci = orderFB[base + lane];
    int sv = starts[ci];
    int ev = ends[ci];
    bool pc = false;
    for (int t = sv; t <= ev; ++t) {
      int l = LE[t], es2 = ES[t];
      pc = pc || ((t > sv) && (l > ev)) || ((t < ev) && (es2 < sv));
    }
    unsigned long long rem = ~__ballot(pc);
    int localCount = 0;
    int ls = 0, le = -1, li = 0;
    while (rem != 0ull && count < NTOP) {
      int t = __ffsll((long long)rem) - 1;
      rem &= rem - 1;
      int s = __shfl(sv, t);
      int e = __shfl(ev, t);
      int cidx = __shfl(ci, t);
      bool ov = (lane < localCount) &&
                (((s < ls) && (ls <= e) && (e < le)) ||
                 ((ls < s) && (s <= le) && (le < e)));
      if (!__any(ov)) {
        if (lane == localCount) { ls = s; le = e; li = cidx; }
        localCount++;
        count++;
      }
    }
    int cbase = count - localCount;
    if (lane < localCount) {
      acc_idx[cbase + lane] = li;
      acc_s[cbase + lane] = ls;
      acc_e[cbase + lane] = le;
      atomicMax(&LE[ls], le);
      atomicMin(&ES[le], ls);
    }
    __syncthreads();
  }
  if (lane == 0) acc_count[0] = count;
}

// ---------------- sort accepted by (start,end), write scalar outputs ----------------
__global__ __launch_bounds__(512) void k_outputs(const int* __restrict__ acc_idx,
                                                 const int* __restrict__ acc_s,
                                                 const int* __restrict__ acc_e,
                                                 const int* __restrict__ acc_count,
                                                 const float* __restrict__ scores,
                                                 const int* __restrict__ speaker,
                                                 float* __restrict__ out,
                                                 int* __restrict__ sortedIdx) {
  __shared__ int ks[NTOP];
  int tid = threadIdx.x;
  int count = acc_count[0];
  int key = 0x7FFFFFFF;
  if (tid < count) key = acc_s[tid] * (NT + 1) + acc_e[tid];
  ks[tid] = key;
  __syncthreads();
  if (tid < count) {
    int r = 0;
    for (int b = 0; b < count; ++b) {
      int kb = ks[b];
      r += ((kb < key) || (kb == key && b < tid)) ? 1 : 0;
    }
    int ci = acc_idx[tid];
    out[OFF_IDX + r] = (float)ci;
    out[OFF_S + r]   = (float)acc_s[tid];
    out[OFF_E + r]   = (float)acc_e[tid];
    out[OFF_SC + r]  = scores[ci];
    out[OFF_SP + r]  = (float)speaker[acc_s[tid]];
    sortedIdx[r] = ci;
  }
  __syncthreads();
  if (tid >= count) {
    out[OFF_IDX + tid] = out[OFF_IDX];
    out[OFF_S + tid]   = out[OFF_S];
    out[OFF_E + tid]   = out[OFF_E];
    out[OFF_SC + tid]  = out[OFF_SC];
    out[OFF_SP + tid]  = out[OFF_SP];
    sortedIdx[tid] = sortedIdx[0];
  }
}

// ---------------- gather pruned_emb rows from span_emb region of d_out ----------------
__global__ __launch_bounds__(256) void k_copy_emb(const int* __restrict__ sortedIdx,
                                                  float* __restrict__ out) {
  int r = blockIdx.x;
  int ci = sortedIdx[r];
  const float* src = out + (size_t)ci * SDIM;
  float* dst = out + OFF_PEMB + (size_t)r * SDIM;
  for (int q = threadIdx.x; q < SDIM / 4; q += 256) {
    ((float4*)dst)[q] = ((const float4*)src)[q];
  }
}

extern "C" void kernel_launch(void* const* d_in, const int* in_sizes, int n_in,
                              void* d_out, int out_size, void* d_ws, size_t ws_size,
                              hipStream_t stream) {
  const float* hidden   = (const float*)d_in[0];
  const int*   starts   = (const int*)d_in[1];
  const int*   ends     = (const int*)d_in[2];
  const int*   speaker  = (const int*)d_in[3];
  const float* w_attn   = (const float*)d_in[4];
  const float* b_attn   = (const float*)d_in[5];
  const float* W1       = (const float*)d_in[6];
  const float* b1       = (const float*)d_in[7];
  const float* W2       = (const float*)d_in[8];
  const float* b2       = (const float*)d_in[9];
  const float* embw     = (const float*)d_in[10];
  const float* ewp      = (const float*)d_in[11];
  const float* Wp1      = (const float*)d_in[12];
  const float* bp1      = (const float*)d_in[13];
  const float* Wp2      = (const float*)d_in[14];
  const float* bp2      = (const float*)d_in[15];
  float* out = (float*)d_out;

  float* f = (float*)d_ws;
  float* P       = f;                            // 6291456 f
  float* expA    = P + 6291456;                  // 2048
  float* Pc      = expA + 2048;                  // 20480
  float* prior   = Pc + 20480;                   // 32
  float* scores  = prior + 32;                   // 40960
  unsigned long long* keys = (unsigned long long*)(scores + 40960);  // 40960 u64
  double* prefPd = (double*)(keys + 40960);      // 2049*1024 d
  double* prefZ  = prefPd + 2049 * 1024;         // 2056 d
  double* chunkSum = prefZ + 2056;               // 32*1800 d
  double* prefH  = chunkSum + 32 * CS_STRIDE;    // 2049*768 d
  // --- contiguous zeroed region: rankS | rank2 | hist | hist64k | survCount | cutB
  int* rankS     = (int*)(prefH + 2049 * 768);   // 40960
  int* rank2     = rankS + 40960;                // 40960
  int* hist      = rank2 + 40960;                // 2048
  int* hist64k   = hist + 2048;                  // 65536
  int* survCount = hist64k + 65536;              // 4
  int* cutB      = survCount + 4;                // 4
  // --- rest (no zero needed)
  int* order     = cutB + 4;                     // 40960
  int* orderFB   = order + 40960;                // 40960
  int* acc_idx   = orderFB + 40960;              // 512
  int* acc_s     = acc_idx + NTOP;
  int* acc_e     = acc_s + NTOP;
  int* acc_count = acc_e + NTOP;                 // 4
  int* flag      = acc_count + 4;                // 4
  int* sortedIdx = flag + 4;                     // 512
  int* cursor    = sortedIdx + NTOP;             // 2048
  int* bases     = cursor + NT;                  // 2056
  int* ord       = bases + 2056;                 // 40960
  int* surv      = ord + 40960;                  // 40960
  unsigned long long* survKey = (unsigned long long*)(surv + 40960);  // 40960 u64

  // one fused zero over [rankS .. cutB] = 149512 ints
  k_zero<<<dim3(585), dim3(256), 0, stream>>>(rankS, 149512);

  // fused setup: hist + expA + Pc + prior
  k_setup<<<dim3(772), dim3(256), 0, stream>>>(starts, hist, hidden, w_attn, b_attn, expA,
                                               embw, W1, Pc, ewp, Wp1, bp1, Wp2, bp2, prior);
  k_prefix<<<dim3(1), dim3(256), 0, stream>>>(hist, cursor, bases);
  k_place<<<dim3(160), dim3(256), 0, stream>>>(starts, cursor, ord);

  k_matmul_P<<<dim3(24, 16), dim3(256), 0, stream>>>(hidden, W1, P);

  // weighted prefix sums (3-pass chunked scan)
  k_psumA<<<dim3(8, NCHUNK), dim3(256), 0, stream>>>(hidden, P, expA, chunkSum);
  k_psumB<<<dim3(8), dim3(256), 0, stream>>>(chunkSum, prefH, prefPd, prefZ);
  k_psumC<<<dim3(8, NCHUNK), dim3(256), 0, stream>>>(hidden, P, expA, chunkSum,
                                                     prefH, prefPd, prefZ);

  // grouped span kernel (bucket histogram fused in)
  k_span2<<<dim3(NT), dim3(256), 0, stream>>>(ord, bases, hidden, ends, embw,
                                              prefH, prefPd, prefZ, P, Pc,
                                              b1, W2, b2, prior, out, scores, keys, hist64k);

  // top-T select + exact rank of survivors
  k_cutoff<<<dim3(1), dim3(1024), 0, stream>>>(hist64k, cutB);
  k_compact<<<dim3(160), dim3(256), 0, stream>>>(keys, cutB, survCount, surv, survKey);
  k_rankT<<<dim3(160, 32), dim3(256), 0, stream>>>(survKey, survCount, rankS);
  k_scatterT<<<dim3(160), dim3(256), 0, stream>>>(surv, rankS, survCount, order);
  k_scanT<<<dim3(1), dim3(64), 0, stream>>>(order, starts, ends, survCount,
                                            acc_idx, acc_s, acc_e, acc_count, flag);

  // guaranteed-correct fallback (early-exits when flag==0)
  k_rank_fb<<<dim3(640), dim3(256), 0, stream>>>(flag, keys, rank2);
  k_scatter_fb<<<dim3(160), dim3(256), 0, stream>>>(flag, rank2, orderFB);
  k_scan_fb<<<dim3(1), dim3(64), 0, stream>>>(flag, orderFB, starts, ends,
                                              acc_idx, acc_s, acc_e, acc_count);

  k_outputs<<<dim3(1), dim3(512), 0, stream>>>(acc_idx, acc_s, acc_e, acc_count, scores,
                                               speaker, out, sortedIdx);
  k_copy_emb<<<dim3(NTOP), dim3(256), 0, stream>>>(sortedIdx, out);
}

// Round 4
// 945.640 us; speedup vs baseline: 1.0850x; 1.0850x over previous
//
#include <hip/hip_runtime.h>
#include <math.h>

#define NT 2048
#define HID 768
#define NC 40960
#define NFEAT 20
#define UN 1024
#define SDIM 2324
#define NTOP 512
#define WMAX 20
#define TOPT 8192

// prefix-scan geometry: 1793 weighted columns (768 hidden | 1024 Pd | 1 Z)
#define NCOLS 1793
#define CHUNK 64
#define NCHUNK 32
#define CS_STRIDE 1800

// d_out element offsets (all f32)
#define OFF_IDX   95191040
#define OFF_S     95191552
#define OFF_E     95192064
#define OFF_PEMB  95192576
#define OFF_SC    96382464
#define OFF_SP    96382976

// ---------------- generic zero ----------------
__global__ void k_zero(int* __restrict__ p, int n) {
  int i = blockIdx.x * 256 + threadIdx.x;
  if (i < n) p[i] = 0;
}

// ---------------- fused: matmul_P | hist | expA | Pc | prior ----------------
// blocks [0,384): matmul P; [384,544): hist; [544,1056): expA; [1056,1136): Pc;
// [1136,1156): prior.  matmul first so its (critical-path) blocks dispatch first.
__global__ __launch_bounds__(256) void k_fused0(
    const float* __restrict__ hidden, const float* __restrict__ W1,
    float* __restrict__ P,
    const int* __restrict__ starts, int* __restrict__ hist,
    const float* __restrict__ w_attn, const float* __restrict__ b_attn,
    float* __restrict__ expA,
    const float* __restrict__ emb_width, float* __restrict__ Pc,
    const float* __restrict__ ewp, const float* __restrict__ Wp1,
    const float* __restrict__ bp1, const float* __restrict__ Wp2,
    const float* __restrict__ bp2, float* __restrict__ prior) {
  __shared__ float smem[16 * 132 + 16 * 128];
  int b = blockIdx.x;
  int tid = threadIdx.x;
  if (b < 384) {                       // ---- P = hidden @ [W1a|W1b|W1d]
    float (*As)[132] = (float(*)[132])smem;
    float (*Bs)[128] = (float(*)[128])(smem + 16 * 132);
    int bn = b % 24, bm = b / 24;
    int n0 = bn * 128;
    int seg = n0 >> 10;
    int rowbase = (seg == 0) ? 0 : (seg == 1 ? HID : (2 * HID + NFEAT));
    int j0 = n0 & 1023;
    int tx = tid & 15, ty = tid >> 4;
    float acc[8][8] = {};
    for (int k0 = 0; k0 < HID; k0 += 16) {
      #pragma unroll
      for (int q = 0; q < 2; ++q) {
        int idx = q * 256 + tid;
        int m = idx >> 2, kg = idx & 3;
        float4 a = *(const float4*)&hidden[(size_t)(bm * 128 + m) * HID + k0 + kg * 4];
        As[kg * 4 + 0][m] = a.x; As[kg * 4 + 1][m] = a.y;
        As[kg * 4 + 2][m] = a.z; As[kg * 4 + 3][m] = a.w;
        int k = idx >> 5, ng = idx & 31;
        float4 bv4 = *(const float4*)&W1[(size_t)(rowbase + k0 + k) * UN + j0 + ng * 4];
        *(float4*)&Bs[k][ng * 4] = bv4;
      }
      __syncthreads();
      #pragma unroll
      for (int k = 0; k < 16; ++k) {
        float4 a0 = *(const float4*)&As[k][ty * 8];
        float4 a1 = *(const float4*)&As[k][ty * 8 + 4];
        float4 b0 = *(const float4*)&Bs[k][tx * 8];
        float4 b1 = *(const float4*)&Bs[k][tx * 8 + 4];
        float av[8] = {a0.x, a0.y, a0.z, a0.w, a1.x, a1.y, a1.z, a1.w};
        float bv[8] = {b0.x, b0.y, b0.z, b0.w, b1.x, b1.y, b1.z, b1.w};
        #pragma unroll
        for (int i = 0; i < 8; ++i)
          #pragma unroll
          for (int jj = 0; jj < 8; ++jj) acc[i][jj] += av[i] * bv[jj];
      }
      __syncthreads();
    }
    #pragma unroll
    for (int i = 0; i < 8; ++i) {
      float* prow = &P[(size_t)(bm * 128 + ty * 8 + i) * 3072 + n0 + tx * 8];
      *(float4*)prow = make_float4(acc[i][0], acc[i][1], acc[i][2], acc[i][3]);
      *(float4*)(prow + 4) = make_float4(acc[i][4], acc[i][5], acc[i][6], acc[i][7]);
    }
    return;
  }
  b -= 384;
  if (b < 160) {                       // ---- hist
    int i = b * 256 + tid;
    atomicAdd(&hist[starts[i]], 1);
    return;
  }
  b -= 160;
  if (b < 512) {                       // ---- expA: one wave per token
    int wave = (b * 256 + tid) >> 6;
    int lane = tid & 63;
    if (wave >= NT) return;
    const float* row = hidden + (size_t)wave * HID;
    float s = 0.f;
    for (int c = lane; c < HID; c += 64) s += row[c] * w_attn[c];
    #pragma unroll
    for (int off = 32; off; off >>= 1) s += __shfl_down(s, off);
    if (lane == 0) expA[wave] = expf(s + b_attn[0]);
    return;
  }
  b -= 512;
  if (b < 80) {                        // ---- Pc[w][j]
    int idx = b * 256 + tid;
    int w = idx >> 10, j = idx & 1023;
    float s = 0.f;
    #pragma unroll
    for (int k = 0; k < NFEAT; ++k) s += emb_width[w * NFEAT + k] * W1[(size_t)(2 * HID + k) * UN + j];
    Pc[idx] = s;
    return;
  }
  b -= 80;
  {                                    // ---- prior[w]
    float* red = smem;
    int w = b;
    float local = 0.f;
    for (int j = tid; j < UN; j += 256) {
      float hp = bp1[j];
      #pragma unroll
      for (int k = 0; k < NFEAT; ++k) hp += ewp[w * NFEAT + k] * Wp1[k * UN + j];
      local += fmaxf(hp, 0.f) * Wp2[j];
    }
    red[tid] = local;
    __syncthreads();
    for (int st = 128; st > 0; st >>= 1) { if (tid < st) red[tid] += red[tid + st]; __syncthreads(); }
    if (tid == 0) prior[w] = red[0] + bp2[0];
  }
}

// ---------------- prefix over hist -> cursor ----------------
__global__ __launch_bounds__(256) void k_prefix(const int* __restrict__ hist,
                                                int* __restrict__ cursor) {
  __shared__ int tsum[256];
  int tid = threadIdx.x;
  int v[8], pre[8];
  int s = 0;
  #pragma unroll
  for (int j = 0; j < 8; ++j) { v[j] = hist[tid * 8 + j]; pre[j] = s; s += v[j]; }
  tsum[tid] = s;
  __syncthreads();
  for (int off = 1; off < 256; off <<= 1) {
    int t = (tid >= off) ? tsum[tid - off] : 0;
    __syncthreads();
    tsum[tid] += t;
    __syncthreads();
  }
  int base = (tid > 0) ? tsum[tid - 1] : 0;
  #pragma unroll
  for (int j = 0; j < 8; ++j) cursor[tid * 8 + j] = base + pre[j];
}

__global__ void k_place(const int* __restrict__ starts, int* __restrict__ cursor,
                        int* __restrict__ ord) {
  int i = blockIdx.x * 256 + threadIdx.x;
  int pos = atomicAdd(&cursor[starts[i]], 1);
  ord[pos] = i;
}

// ---------------- weighted prefix scan over [hidden(768) | Pd(1024) | 1] ----------------
__global__ __launch_bounds__(256) void k_psumA(const float* __restrict__ hidden,
                                               const float* __restrict__ P,
                                               const float* __restrict__ expA,
                                               double* __restrict__ chunkSum) {
  int col = blockIdx.x * 256 + threadIdx.x;
  int ch = blockIdx.y;
  if (col >= NCOLS) return;
  double acc = 0.0;
  int t0 = ch * CHUNK;
  if (col < HID) {
    const float* p = hidden + col;
    #pragma unroll 8
    for (int r = 0; r < CHUNK; ++r) {
      int t = t0 + r;
      acc += (double)expA[t] * (double)p[(size_t)t * HID];
    }
  } else if (col < HID + UN) {
    const float* p = P + 2048 + (col - HID);
    #pragma unroll 8
    for (int r = 0; r < CHUNK; ++r) {
      int t = t0 + r;
      acc += (double)expA[t] * (double)p[(size_t)t * 3072];
    }
  } else {
    #pragma unroll 8
    for (int r = 0; r < CHUNK; ++r) acc += (double)expA[t0 + r];
  }
  chunkSum[(size_t)ch * CS_STRIDE + col] = acc;
}

__global__ __launch_bounds__(256) void k_psumB(double* __restrict__ chunkSum,
                                               double* __restrict__ prefH,
                                               double* __restrict__ prefPd,
                                               double* __restrict__ prefZ) {
  int col = blockIdx.x * 256 + threadIdx.x;
  if (col >= NCOLS) return;
  double run = 0.0;
  for (int ch = 0; ch < NCHUNK; ++ch) {
    size_t o = (size_t)ch * CS_STRIDE + col;
    double v = chunkSum[o];
    chunkSum[o] = run;
    run += v;
  }
  if (col < HID) prefH[col] = 0.0;
  else if (col < HID + UN) prefPd[col - HID] = 0.0;
  else prefZ[0] = 0.0;
}

__global__ __launch_bounds__(256) void k_psumC(const float* __restrict__ hidden,
                                               const float* __restrict__ P,
                                               const float* __restrict__ expA,
                                               const double* __restrict__ chunkSum,
                                               double* __restrict__ prefH,
                                               double* __restrict__ prefPd,
                                               double* __restrict__ prefZ) {
  int col = blockIdx.x * 256 + threadIdx.x;
  int ch = blockIdx.y;
  if (col >= NCOLS) return;
  double acc = chunkSum[(size_t)ch * CS_STRIDE + col];
  int t0 = ch * CHUNK;
  if (col < HID) {
    const float* p = hidden + col;
    double* o = prefH + col;
    #pragma unroll 4
    for (int r = 0; r < CHUNK; ++r) {
      int t = t0 + r;
      acc += (double)expA[t] * (double)p[(size_t)t * HID];
      o[(size_t)(t + 1) * HID] = acc;
    }
  } else if (col < HID + UN) {
    int c = col - HID;
    const float* p = P + 2048 + c;
    double* o = prefPd + c;
    #pragma unroll 4
    for (int r = 0; r < CHUNK; ++r) {
      int t = t0 + r;
      acc += (double)expA[t] * (double)p[(size_t)t * 3072];
      o[(size_t)(t + 1) * UN] = acc;
    }
  } else {
    #pragma unroll 4
    for (int r = 0; r < CHUNK; ++r) {
      int t = t0 + r;
      acc += (double)expA[t];
      prefZ[t + 1] = acc;
    }
  }
}

// ---------------- fused span_emb write + score via prefix differences ----------------
// (per-candidate form — measured fastest; ord gives ascending-start L2 locality)
__global__ __launch_bounds__(256) void k_span(
    const int* __restrict__ ord,
    const float* __restrict__ hidden, const int* __restrict__ starts, const int* __restrict__ ends,
    const float* __restrict__ emb_width,
    const double* __restrict__ prefH, const double* __restrict__ prefPd,
    const double* __restrict__ prefZ,
    const float* __restrict__ P, const float* __restrict__ Pc,
    const float* __restrict__ b1, const float* __restrict__ W2,
    const float* __restrict__ b2ptr, const float* __restrict__ prior,
    float* __restrict__ out, float* __restrict__ scores,
    unsigned long long* __restrict__ keys, int* __restrict__ hist64k) {
  int i = ord[blockIdx.x];
  int s = starts[i], e = ends[i];
  int w = e - s;
  int tid = threadIdx.x;
  double invZ = 1.0 / (prefZ[e + 1] - prefZ[s]);
  const float* hs = hidden + (size_t)s * HID;
  const float* he = hidden + (size_t)e * HID;
  const double* pHs = prefH + (size_t)s * HID;
  const double* pHe = prefH + (size_t)(e + 1) * HID;
  float* orow = out + (size_t)i * SDIM;
  for (int q = tid; q < SDIM / 4; q += 256) {
    int c = q * 4;
    float4 v;
    if (c < HID) v = *(const float4*)(hs + c);
    else if (c < 2 * HID) v = *(const float4*)(he + (c - HID));
    else if (c < 2 * HID + NFEAT) v = *(const float4*)(emb_width + w * NFEAT + (c - 2 * HID));
    else {
      int cc = c - (2 * HID + NFEAT);
      const double* pe = pHe + cc;
      const double* ps = pHs + cc;
      v = make_float4((float)((pe[0] - ps[0]) * invZ),
                      (float)((pe[1] - ps[1]) * invZ),
                      (float)((pe[2] - ps[2]) * invZ),
                      (float)((pe[3] - ps[3]) * invZ));
    }
    *(float4*)(orow + c) = v;
  }
  // score: pre_h = b1 + Pa[s] + Pb[e] + Pc[w] + (prefPd[e+1]-prefPd[s])/Z
  int j = tid * 4;
  float4 pre = *(const float4*)(b1 + j);
  float4 pa = *(const float4*)(P + (size_t)s * 3072 + j);
  float4 pb = *(const float4*)(P + (size_t)e * 3072 + 1024 + j);
  float4 pc = *(const float4*)(Pc + w * UN + j);
  const double* pds = prefPd + (size_t)s * UN + j;
  const double* pde = prefPd + (size_t)(e + 1) * UN + j;
  pre.x += pa.x + pb.x + pc.x + (float)((pde[0] - pds[0]) * invZ);
  pre.y += pa.y + pb.y + pc.y + (float)((pde[1] - pds[1]) * invZ);
  pre.z += pa.z + pb.z + pc.z + (float)((pde[2] - pds[2]) * invZ);
  pre.w += pa.w + pb.w + pc.w + (float)((pde[3] - pds[3]) * invZ);
  float4 w2 = *(const float4*)(W2 + j);
  float local = fmaxf(pre.x, 0.f) * w2.x + fmaxf(pre.y, 0.f) * w2.y +
                fmaxf(pre.z, 0.f) * w2.z + fmaxf(pre.w, 0.f) * w2.w;
  #pragma unroll
  for (int off = 32; off; off >>= 1) local += __shfl_down(local, off);
  __shared__ float red[4];
  if ((tid & 63) == 0) red[tid >> 6] = local;
  __syncthreads();
  if (tid == 0) {
    float sc = red[0] + red[1] + red[2] + red[3] + b2ptr[0] + prior[w];
    scores[i] = sc;
    unsigned u = __float_as_uint(sc);
    u = (u >> 31) ? ~u : (u | 0x80000000u);        // ascending-order map
    unsigned inv = ~u;                             // descending score
    keys[i] = (((unsigned long long)inv) << 32) | (unsigned)i;
    atomicAdd(&hist64k[(int)(inv >> 16)], 1);      // fused bucket histogram
  }
}

// ---------------- find smallest bucket B with cum(<=B) >= TOPT ----------------
__global__ __launch_bounds__(1024) void k_cutoff(const int* __restrict__ hist64k,
                                                 int* __restrict__ cutB) {
  __shared__ int psum[1024];
  int tid = threadIdx.x;
  int base = tid * 64;
  int s = 0;
  #pragma unroll
  for (int j = 0; j < 16; ++j) {
    int4 v = *(const int4*)&hist64k[base + j * 4];
    s += v.x + v.y + v.z + v.w;
  }
  psum[tid] = s;
  __syncthreads();
  for (int off = 1; off < 1024; off <<= 1) {
    int t = (tid >= off) ? psum[tid - off] : 0;
    __syncthreads();
    psum[tid] += t;
    __syncthreads();
  }
  int cumEnd = psum[tid];
  int cumStart = cumEnd - s;
  if (cumStart < TOPT && TOPT <= cumEnd) {
    int run = cumStart;
    for (int j = 0; j < 64; ++j) {
      run += hist64k[base + j];
      if (run >= TOPT) { cutB[0] = base + j; break; }
    }
  }
}

__global__ void k_compact(const unsigned long long* __restrict__ keys,
                          const int* __restrict__ cutB,
                          int* __restrict__ survCount,
                          int* __restrict__ surv,
                          unsigned long long* __restrict__ survKey) {
  int i = blockIdx.x * 256 + threadIdx.x;
  int B = cutB[0];
  unsigned long long k = keys[i];
  bool keep = ((int)(k >> 48)) <= B;
  unsigned long long m = __ballot(keep);
  if (m == 0ull) return;
  int lane = threadIdx.x & 63;
  int leader = __ffsll((long long)m) - 1;
  int pos = 0;
  if (lane == leader) pos = atomicAdd(survCount, __popcll(m));
  pos = __shfl(pos, leader);
  if (keep) {
    int slot = pos + __popcll(m & ((1ull << lane) - 1ull));
    surv[slot] = i;
    survKey[slot] = k;
  }
}

// exact rank among survivors (S ~ TOPT + one-bucket slack)
__global__ __launch_bounds__(256) void k_rankT(const unsigned long long* __restrict__ survKey,
                                               const int* __restrict__ survCount,
                                               int* __restrict__ rankS) {
  int S = survCount[0];
  int i = blockIdx.x * 256 + threadIdx.x;
  int j0 = blockIdx.y * 1280;
  if (i >= S || j0 >= S) return;
  int j1 = min(j0 + 1280, S);
  unsigned long long mk = survKey[i];
  int cnt = 0;
  for (int j = j0; j < j1; ++j) cnt += (survKey[j] < mk) ? 1 : 0;
  if (cnt) atomicAdd(&rankS[i], cnt);
}

__global__ void k_scatterT(const int* __restrict__ surv, const int* __restrict__ rankS,
                           const int* __restrict__ survCount, int* __restrict__ order) {
  int t = blockIdx.x * 256 + threadIdx.x;
  if (t < survCount[0]) order[rankS[t]] = surv[t];
}

// ---------------- greedy NMS over top-S survivors, survivor-skip serial loop --------
__global__ void k_scanT(const int* __restrict__ order,
                        const int* __restrict__ starts,
                        const int* __restrict__ ends,
                        const int* __restrict__ survCount,
                        int* __restrict__ acc_idx, int* __restrict__ acc_s,
                        int* __restrict__ acc_e, int* __restrict__ acc_count,
                        int* __restrict__ flag) {
  __shared__ int LE[NT];
  __shared__ int ES[NT];
  int lane = threadIdx.x;
  int S = survCount[0];
  for (int t = lane; t < NT; t += 64) { LE[t] = -1; ES[t] = NT; }
  __syncthreads();
  int count = 0;
  for (int base = 0; base < S && count < NTOP; base += 64) {
    int idx = base + lane;
    bool valid = idx < S;
    int ci = order[valid ? idx : 0];
    int sv = starts[ci];
    int ev = ends[ci];
    bool pc = !valid;
    for (int t = sv; t <= ev; ++t) {
      int l = LE[t], es2 = ES[t];
      pc = pc || ((t > sv) && (l > ev)) || ((t < ev) && (es2 < sv));
    }
    unsigned long long rem = ~__ballot(pc);
    int localCount = 0;
    int ls = 0, le = -1, li = 0;
    while (rem != 0ull && count < NTOP) {
      int t = __ffsll((long long)rem) - 1;
      rem &= rem - 1;
      int s = __shfl(sv, t);
      int e = __shfl(ev, t);
      int cidx = __shfl(ci, t);
      bool ov = (lane < localCount) &&
                (((s < ls) && (ls <= e) && (e < le)) ||
                 ((ls < s) && (s <= le) && (le < e)));
      if (!__any(ov)) {
        if (lane == localCount) { ls = s; le = e; li = cidx; }
        localCount++;
        count++;
      }
    }
    int cbase = count - localCount;
    if (lane < localCount) {
      acc_idx[cbase + lane] = li;
      acc_s[cbase + lane] = ls;
      acc_e[cbase + lane] = le;
      atomicMax(&LE[ls], le);
      atomicMin(&ES[le], ls);
    }
    __syncthreads();
  }
  if (lane == 0) {
    acc_count[0] = count;
    flag[0] = (count < NTOP && S < NC) ? 1 : 0;
  }
}

// ---------------- fallback path (flag-gated; ~never runs) ----------------
__global__ __launch_bounds__(256) void k_rank_fb(const int* __restrict__ flag,
                                                 const unsigned long long* __restrict__ keys,
                                                 int* __restrict__ rank2) {
  if (!flag[0]) return;
  int ic = blockIdx.x >> 5;
  int jc = blockIdx.x & 31;
  int tid = threadIdx.x;
  int ibase = ic * 2048 + tid;
  unsigned long long mk[8];
  int cnt[8];
  #pragma unroll
  for (int k = 0; k < 8; ++k) { mk[k] = keys[ibase + k * 256]; cnt[k] = 0; }
  int j0 = jc * 1280;
  #pragma unroll 4
  for (int j = j0; j < j0 + 1280; ++j) {
    unsigned long long kj = keys[j];
    #pragma unroll
    for (int k = 0; k < 8; ++k) cnt[k] += (kj < mk[k]) ? 1 : 0;
  }
  #pragma unroll
  for (int k = 0; k < 8; ++k) if (cnt[k]) atomicAdd(&rank2[ibase + k * 256], cnt[k]);
}

__global__ void k_scatter_fb(const int* __restrict__ flag, const int* __restrict__ rank2,
                             int* __restrict__ orderFB) {
  if (!flag[0]) return;
  int i = blockIdx.x * 256 + threadIdx.x;
  orderFB[rank2[i]] = i;
}

__global__ void k_scan_fb(const int* __restrict__ flag,
                          const int* __restrict__ orderFB,
                          const int* __restrict__ starts,
                          const int* __restrict__ ends,
                          int* __restrict__ acc_idx, int* __restrict__ acc_s,
                          int* __restrict__ acc_e, int* __restrict__ acc_count) {
  if (!flag[0]) return;
  __shared__ int LE[NT];
  __shared__ int ES[NT];
  int lane = threadIdx.x;
  for (int t = lane; t < NT; t += 64) { LE[t] = -1; ES[t] = NT; }
  __syncthreads();
  int count = 0;
  for (int base = 0; base < NC && count < NTOP; base += 64) {
    int ci = orderFB[base + lane];
    int sv = starts[ci];
    int ev = ends[ci];
    bool pc = false;
    for (int t = sv; t <= ev; ++t) {
      int l = LE[t], es2 = ES[t];
      pc = pc || ((t > sv) && (l > ev)) || ((t < ev) && (es2 < sv));
    }
    unsigned long long rem = ~__ballot(pc);
    int localCount = 0;
    int ls = 0, le = -1, li = 0;
    while (rem != 0ull && count < NTOP) {
      int t = __ffsll((long long)rem) - 1;
      rem &= rem - 1;
      int s = __shfl(sv, t);
      int e = __shfl(ev, t);
      int cidx = __shfl(ci, t);
      bool ov = (lane < localCount) &&
                (((s < ls) && (ls <= e) && (e < le)) ||
                 ((ls < s) && (s <= le) && (le < e)));
      if (!__any(ov)) {
        if (lane == localCount) { ls = s; le = e; li = cidx; }
        localCount++;
        count++;
      }
    }
    int cbase = count - localCount;
    if (lane < localCount) {
      acc_idx[cbase + lane] = li;
      acc_s[cbase + lane] = ls;
      acc_e[cbase + lane] = le;
      atomicMax(&LE[ls], le);
      atomicMin(&ES[le], ls);
    }
    __syncthreads();
  }
  if (lane == 0) acc_count[0] = count;
}

// ---------------- merged: per-block rank + scalar outputs + pruned_emb copy --------
// block b handles accepted entry b (or, if b >= count, the fill row b = rank-0 copy).
__global__ __launch_bounds__(256) void k_out_copy(
    const int* __restrict__ acc_idx, const int* __restrict__ acc_s,
    const int* __restrict__ acc_e, const int* __restrict__ acc_count,
    const float* __restrict__ scores, const int* __restrict__ speaker,
    float* __restrict__ out) {
  __shared__ int ks[NTOP];
  __shared__ int redi[256];
  __shared__ long long redl[256];
  int b = blockIdx.x;
  int tid = threadIdx.x;
  int count = acc_count[0];
  for (int q = tid; q < NTOP; q += 256)
    ks[q] = (q < count) ? acc_s[q] * (NT + 1) + acc_e[q] : 0x7FFFFFFF;
  __syncthreads();
  int r, ci, sv, ev;
  if (b < count) {
    int key = ks[b];
    int cnt = 0;
    for (int q = tid; q < count; q += 256) {
      int kb = ks[q];
      cnt += ((kb < key) || (kb == key && q < b)) ? 1 : 0;
    }
    redi[tid] = cnt;
    __syncthreads();
    for (int st = 128; st > 0; st >>= 1) { if (tid < st) redi[tid] += redi[tid + st]; __syncthreads(); }
    r = redi[0];
    ci = acc_idx[b]; sv = acc_s[b]; ev = acc_e[b];
  } else {
    // rank-0 entry = accepted with min (start,end) key, tie smaller index
    long long best = 0x7FFFFFFFFFFFLL;
    for (int q = tid; q < count; q += 256) {
      long long p = ((long long)ks[q] << 10) | q;
      best = (p < best) ? p : best;
    }
    redl[tid] = best;
    __syncthreads();
    for (int st = 128; st > 0; st >>= 1) {
      if (tid < st) redl[tid] = (redl[tid + st] < redl[tid]) ? redl[tid + st] : redl[tid];
      __syncthreads();
    }
    int j0 = (int)(redl[0] & 1023);
    r = b;
    ci = acc_idx[j0]; sv = acc_s[j0]; ev = acc_e[j0];
  }
  if (tid == 0) {
    out[OFF_IDX + r] = (float)ci;
    out[OFF_S + r]   = (float)sv;
    out[OFF_E + r]   = (float)ev;
    out[OFF_SC + r]  = scores[ci];
    out[OFF_SP + r]  = (float)speaker[sv];
  }
  const float* src = out + (size_t)ci * SDIM;
  float* dst = out + OFF_PEMB + (size_t)r * SDIM;
  for (int q = tid; q < SDIM / 4; q += 256) {
    ((float4*)dst)[q] = ((const float4*)src)[q];
  }
}

extern "C" void kernel_launch(void* const* d_in, const int* in_sizes, int n_in,
                              void* d_out, int out_size, void* d_ws, size_t ws_size,
                              hipStream_t stream) {
  const float* hidden   = (const float*)d_in[0];
  const int*   starts   = (const int*)d_in[1];
  const int*   ends     = (const int*)d_in[2];
  const int*   speaker  = (const int*)d_in[3];
  const float* w_attn   = (const float*)d_in[4];
  const float* b_attn   = (const float*)d_in[5];
  const float* W1       = (const float*)d_in[6];
  const float* b1       = (const float*)d_in[7];
  const float* W2       = (const float*)d_in[8];
  const float* b2       = (const float*)d_in[9];
  const float* embw     = (const float*)d_in[10];
  const float* ewp      = (const float*)d_in[11];
  const float* Wp1      = (const float*)d_in[12];
  const float* bp1      = (const float*)d_in[13];
  const float* Wp2      = (const float*)d_in[14];
  const float* bp2      = (const float*)d_in[15];
  float* out = (float*)d_out;

  float* f = (float*)d_ws;
  float* P       = f;                            // 6291456 f
  float* expA    = P + 6291456;                  // 2048
  float* Pc      = expA + 2048;                  // 20480
  float* prior   = Pc + 20480;                   // 32
  float* scores  = prior + 32;                   // 40960
  unsigned long long* keys = (unsigned long long*)(scores + 40960);  // 40960 u64
  double* prefPd = (double*)(keys + 40960);      // 2049*1024 d
  double* prefZ  = prefPd + 2049 * 1024;         // 2056 d
  double* chunkSum = prefZ + 2056;               // 32*1800 d
  double* prefH  = chunkSum + 32 * CS_STRIDE;    // 2049*768 d
  // --- contiguous zeroed region: rankS | rank2 | hist | hist64k | survCount | cutB
  int* rankS     = (int*)(prefH + 2049 * 768);   // 40960
  int* rank2     = rankS + 40960;                // 40960
  int* hist      = rank2 + 40960;                // 2048
  int* hist64k   = hist + 2048;                  // 65536
  int* survCount = hist64k + 65536;              // 4
  int* cutB      = survCount + 4;                // 4
  // --- rest (no zero needed)
  int* order     = cutB + 4;                     // 40960
  int* orderFB   = order + 40960;                // 40960
  int* acc_idx   = orderFB + 40960;              // 512
  int* acc_s     = acc_idx + NTOP;
  int* acc_e     = acc_s + NTOP;
  int* acc_count = acc_e + NTOP;                 // 4
  int* flag      = acc_count + 4;                // 4
  int* cursor    = flag + 4;                     // 2048
  int* ord       = cursor + NT;                  // 40960
  int* surv      = ord + 40960;                  // 40960
  unsigned long long* survKey = (unsigned long long*)(surv + 40960);  // 40960 u64

  // one fused zero over [rankS .. cutB] = 149512 ints
  k_zero<<<dim3(585), dim3(256), 0, stream>>>(rankS, 149512);

  // fused: matmul_P + hist + expA + Pc + prior (independent work, one launch)
  k_fused0<<<dim3(1156), dim3(256), 0, stream>>>(hidden, W1, P, starts, hist,
                                                 w_attn, b_attn, expA, embw, Pc,
                                                 ewp, Wp1, bp1, Wp2, bp2, prior);
  k_prefix<<<dim3(1), dim3(256), 0, stream>>>(hist, cursor);
  k_place<<<dim3(160), dim3(256), 0, stream>>>(starts, cursor, ord);

  // weighted prefix sums (3-pass chunked scan)
  k_psumA<<<dim3(8, NCHUNK), dim3(256), 0, stream>>>(hidden, P, expA, chunkSum);
  k_psumB<<<dim3(8), dim3(256), 0, stream>>>(chunkSum, prefH, prefPd, prefZ);
  k_psumC<<<dim3(8, NCHUNK), dim3(256), 0, stream>>>(hidden, P, expA, chunkSum,
                                                     prefH, prefPd, prefZ);

  // per-candidate span kernel (bucket histogram fused in)
  k_span<<<dim3(NC), dim3(256), 0, stream>>>(ord, hidden, starts, ends, embw,
                                             prefH, prefPd, prefZ, P, Pc,
                                             b1, W2, b2, prior, out, scores, keys, hist64k);

  // top-T select + exact rank of survivors
  k_cutoff<<<dim3(1), dim3(1024), 0, stream>>>(hist64k, cutB);
  k_compact<<<dim3(160), dim3(256), 0, stream>>>(keys, cutB, survCount, surv, survKey);
  k_rankT<<<dim3(160, 32), dim3(256), 0, stream>>>(survKey, survCount, rankS);
  k_scatterT<<<dim3(160), dim3(256), 0, stream>>>(surv, rankS, survCount, order);
  k_scanT<<<dim3(1), dim3(64), 0, stream>>>(order, starts, ends, survCount,
                                            acc_idx, acc_s, acc_e, acc_count, flag);

  // guaranteed-correct fallback (early-exits when flag==0)
  k_rank_fb<<<dim3(640), dim3(256), 0, stream>>>(flag, keys, rank2);
  k_scatter_fb<<<dim3(160), dim3(256), 0, stream>>>(flag, rank2, orderFB);
  k_scan_fb<<<dim3(1), dim3(64), 0, stream>>>(flag, orderFB, starts, ends,
                                              acc_idx, acc_s, acc_e, acc_count);

  // merged outputs + pruned_emb copy
  k_out_copy<<<dim3(NTOP), dim3(256), 0, stream>>>(acc_idx, acc_s, acc_e, acc_count,
                                                   scores, speaker, out);
}